// Round 2
// baseline (119.705 us; speedup 1.0000x reference)
//
#include <hip/hip_runtime.h>
#include <hip/hip_fp16.h>
#include <stdint.h>

#define BATCH  4
#define CCH    128
#define GRID_H 128
#define GRID_W 128
#define NNODE  (GRID_H*GRID_W)   // 16384
#define NHEAD  8
#define DH     16
#define WPAD   68                // padded k2 row (64 + 4), keeps b128 align
#define WROWS  144               // 128 ch + 8 aS + 8 aD

typedef __attribute__((ext_vector_type(8))) short short8;
typedef __attribute__((ext_vector_type(4))) float f32x4;
typedef __attribute__((ext_vector_type(4))) unsigned u32x4;

__device__ inline unsigned packbf(float a, float b){
    unsigned r;
    asm("v_cvt_pk_bf16_f32 %0, %1, %2" : "=v"(r) : "v"(a), "v"(b));
    return r;   // {lo,hi} = {bf16(a),bf16(b)} (order-agnostic for the GEMM: both
                // operands pair k-values identically, dot is permutation-invariant)
}
__device__ inline unsigned packhf(float a, float b){
    unsigned r;
    asm("v_cvt_pkrtz_f16_f32 %0, %1, %2" : "=v"(r) : "v"(a), "v"(b));
    return r;
}

// ---------------------------------------------------------------------------
// kA: fused W'-pack prologue + original-orientation GEMM (A=x, B=W') +
// original per-element epilogue. Changes vs 117.6us baseline ONLY:
//  - kW kernel fused in (W' packed to bf16 k-pairs in LDS from Wl/attS/attD)
//  - packbf via v_cvt_pk_bf16_f32 (1 VALU op per pair vs ~10)
//  - xp emitted as f16 (scalar v_cvt_f16_f32) -> kB uses v_pk_fma_f16
//  - scores written split (scS | scD) instead of interleaved float2
//  - XCD band swizzle: row band [16x,16x+16) -> XCD x
// ---------------------------------------------------------------------------
__global__ __launch_bounds__(256, 3) void kA(
    const float* __restrict__ x,   const float* __restrict__ Wl,
    const float* __restrict__ attS, const float* __restrict__ attD,
    __half* __restrict__ xpb, float* __restrict__ scS, float* __restrict__ scD)
{
    __shared__ __align__(16) unsigned WbL[WROWS*WPAD];   // 39168 B
    __shared__ __align__(16) float att2[2*CCH];          // 1 KB
    __shared__ float Wa[CCH][17];                        // 8704 B

    const int t  = threadIdx.x;
    const int b  = blockIdx.y;
    const int bx = blockIdx.x;
    const int row = (bx & 7)*16 + (bx >> 3);             // bijective over 128 rows
    const int n0  = row * GRID_W;

    // ---- prologue 1: stage attention vectors (attS|attD, 256 floats) ----
    att2[t] = (t < CCH) ? attS[t] : attD[t - CCH];
    __syncthreads();

    // ---- prologue 2: Wa[k][j] = dot(Wl[k][(j&7)*16 .. +16], att_j) ----
    {
        const int j = t & 15;
        f32x4 av[4];
        #pragma unroll
        for (int d4 = 0; d4 < 4; ++d4) av[d4] = *(const f32x4*)&att2[j*16 + d4*4];
        #pragma unroll
        for (int it = 0; it < 8; ++it){
            const int k = it*16 + (t >> 4);
            const float* wr = Wl + (size_t)k*CCH + (j & 7)*16;
            float s = 0.f;
            #pragma unroll
            for (int d4 = 0; d4 < 4; ++d4){
                f32x4 wv = *(const f32x4*)(wr + d4*4);
                s += wv[0]*av[d4][0] + wv[1]*av[d4][1] + wv[2]*av[d4][2] + wv[3]*av[d4][3];
            }
            Wa[k][j] = s;
        }
    }
    __syncthreads();

    // ---- prologue 3: pack W' (144 x 128) bf16 k-pairs, co-major, to LDS ----
    {
        const int k2 = t >> 2, cb = t & 3;               // k2 0..63, co-block 0..3
        const float* r0 = Wl + (size_t)(2*k2)*CCH + cb*32;
        const float* r1 = r0 + CCH;
        #pragma unroll
        for (int i4 = 0; i4 < 8; ++i4){
            f32x4 a = *(const f32x4*)(r0 + i4*4);
            f32x4 c = *(const f32x4*)(r1 + i4*4);
            #pragma unroll
            for (int u = 0; u < 4; ++u)
                WbL[(cb*32 + i4*4 + u)*WPAD + k2] = packbf(a[u], c[u]);
        }
        #pragma unroll
        for (int jj = 0; jj < 4; ++jj){
            const int j = cb*4 + jj;
            WbL[(CCH + j)*WPAD + k2] = packbf(Wa[2*k2][j], Wa[2*k2+1][j]);
        }
    }
    __syncthreads();

    // ---- main loop: ORIGINAL orientation (A = x-frag, B = W'-frag) ----
    const int w = t >> 6, lane = t & 63;
    const int col = lane & 15, q = lane >> 4;
    const float* xb = x + (size_t)b*CCH*NNODE;
    const int nA = n0 + (2*w+0)*16 + col;
    const int nB = n0 + (2*w+1)*16 + col;

    f32x4 acc[2][9];
    #pragma unroll
    for (int mi = 0; mi < 2; ++mi)
        #pragma unroll
        for (int ct = 0; ct < 9; ++ct) acc[mi][ct] = (f32x4)(0.f);

    float xrA[8], xrB[8], x2A[8], x2B[8];
    #pragma unroll
    for (int j = 0; j < 8; ++j){
        const size_t co = (size_t)(q*8 + j)*NNODE;
        xrA[j] = xb[co + nA];
        xrB[j] = xb[co + nB];
    }

    union U { u32x4 u; short8 s; };
    #pragma unroll
    for (int kc = 0; kc < 4; ++kc){
        if (kc < 3){
            #pragma unroll
            for (int j = 0; j < 8; ++j){
                const size_t co = (size_t)((kc+1)*32 + q*8 + j)*NNODE;
                x2A[j] = xb[co + nA];
                x2B[j] = xb[co + nB];
            }
        }
        U fa0, fa1;
        #pragma unroll
        for (int i = 0; i < 4; ++i){
            fa0.u[i] = packbf(xrA[2*i], xrA[2*i+1]);
            fa1.u[i] = packbf(xrB[2*i], xrB[2*i+1]);
        }
        const int kof = kc*16 + q*4;
        #pragma unroll
        for (int ct = 0; ct < 9; ++ct){
            U fb; fb.u = *(const u32x4*)(&WbL[(ct*16+col)*WPAD + kof]);
            acc[0][ct] = __builtin_amdgcn_mfma_f32_16x16x32_bf16(fa0.s, fb.s, acc[0][ct], 0, 0, 0);
            acc[1][ct] = __builtin_amdgcn_mfma_f32_16x16x32_bf16(fa1.s, fb.s, acc[1][ct], 0, 0, 0);
        }
        #pragma unroll
        for (int j = 0; j < 8; ++j){ xrA[j] = x2A[j]; xrB[j] = x2B[j]; }
    }

    // ---- epilogue: ORIGINAL per-element layout; f16 xp, split scores ----
    // D layout (m91): col=lane&15 -> channel ct*16+col ; row=q*4+r -> node
    __half* xr = xpb + (size_t)b*NNODE*CCH;
    float*  sS = scS + (size_t)b*NNODE*NHEAD;
    float*  sD = scD + (size_t)b*NNODE*NHEAD;
    #pragma unroll
    for (int mi = 0; mi < 2; ++mi){
        #pragma unroll
        for (int r = 0; r < 4; ++r){
            const int n = n0 + (2*w+mi)*16 + q*4 + r;
            #pragma unroll
            for (int ct = 0; ct < 8; ++ct)
                xr[(size_t)n*CCH + ct*16 + col] = __float2half(acc[mi][ct][r]);
            const float v = acc[mi][8][r];               // aug index j = col
            if (col < 8) sS[(size_t)n*NHEAD + col]     = v;
            else         sD[(size_t)n*NHEAD + col - 8] = v;
        }
    }
}

// ---------------------------------------------------------------------------
// kB: 64 nodes/block; half-wave per node; 2-deep pipeline.
//  - scores split scS/scD: 4B aS per edge + one aD per node
//  - xp is f16: aggregation via v_pk_fma_f16 (__hfma2), no unpack VALU
//  - XCD band swizzle matching kA's producer bands
// ---------------------------------------------------------------------------
__device__ inline void kb_issue(int n, const float* __restrict__ scSb,
                                const float* __restrict__ scDb,
                                const uint2* __restrict__ xvb, int h, int l2,
                                int* vm, float aS[9], float* aD, uint2 xv[9])
{
    const int rr = n >> 7, cc = n & 127;
    const bool vU = rr > 0, vD = rr < GRID_H-1, vL = cc > 0, vR = cc < GRID_W-1;
    int m = 0;
    #pragma unroll
    for (int e = 0; e < 9; ++e){
        const int dr = e/3 - 1, dc = e%3 - 1;
        const bool vr_ = (dr < 0) ? vU : (dr > 0 ? vD : true);
        const bool vc_ = (dc < 0) ? vL : (dc > 0 ? vR : true);
        const bool v = vr_ && vc_;
        const int src = v ? (n + dr*GRID_W + dc) : n;
        m |= ((int)v) << e;
        aS[e] = scSb[src*NHEAD + h];
        xv[e] = xvb[(size_t)src*32 + l2];
    }
    *aD = scDb[n*NHEAD + h];
    *vm = m;
}

__global__ __launch_bounds__(256, 3) void kB(
    const __half* __restrict__ xpb, const float* __restrict__ scS,
    const float* __restrict__ scD,
    const float* __restrict__ bias, const float* __restrict__ gamma,
    const float* __restrict__ beta, float* __restrict__ out)
{
    __shared__ float outT[CCH][65];
    const int t = threadIdx.x, w = t >> 6, lane = t & 63;
    const int h2 = lane >> 5, l2 = lane & 31;
    const int b  = blockIdx.y;
    const int bx = blockIdx.x;
    const int xcd = bx & 7, rest = bx >> 3;
    const int hlf = rest & 1, rowin = rest >> 1;
    const int n0  = (xcd*16 + rowin)*GRID_W + hlf*64;    // bijective over 256 blocks

    const uint2* xvb  = (const uint2*)(xpb + (size_t)b*NNODE*CCH);
    const float* scSb = scS + (size_t)b*NNODE*NHEAD;
    const float* scDb = scD + (size_t)b*NNODE*NHEAD;
    const int h = l2 >> 2;
    const f32x4 bi = *(const f32x4*)(bias  + 4*l2);
    const f32x4 ga = *(const f32x4*)(gamma + 4*l2);
    const f32x4 be = *(const f32x4*)(beta  + 4*l2);

    float aSP[2][9]; uint2 xvP[2][9]; float aDP[2]; int vmP[2];

    #define NODE(i) (n0 + w*16 + 2*(i) + h2)
    kb_issue(NODE(0), scSb, scDb, xvb, h, l2, &vmP[0], aSP[0], &aDP[0], xvP[0]);

    #pragma unroll
    for (int ii = 0; ii < 4; ++ii){
        #pragma unroll
        for (int ph = 0; ph < 2; ++ph){
            const int i = 2*ii + ph;
            const int cur = i & 1;
            if (i + 1 < 8)
                kb_issue(NODE(i+1), scSb, scDb, xvb, h, l2,
                         &vmP[cur^1], aSP[cur^1], &aDP[cur^1], xvP[cur^1]);

            const int vm = vmP[cur];
            const float* aS = aSP[cur];
            const uint2*  xv = xvP[cur];
            const float ad = aDP[cur];
            const int nl = w*16 + 2*i + h2;

            float s[9], mx = -1e30f;
            #pragma unroll
            for (int e = 0; e < 9; ++e){
                float sv = aS[e] + ad;
                sv = fmaxf(sv, 0.2f*sv);
                s[e] = ((vm >> e) & 1) ? sv : -1e30f;
                mx = fmaxf(mx, s[e]);
            }
            float wt[9], den = 0.f;
            #pragma unroll
            for (int e = 0; e < 9; ++e){
                float ex = __expf(s[e] - mx);
                ex = ((vm >> e) & 1) ? ex : 0.f;
                wt[e] = ex; den += ex;
            }
            den += wt[4];                                // add_self_loops duplicate
            const float inv = __builtin_amdgcn_rcpf(den);

            union HU { unsigned u; __half2 h; };
            HU a01, a23; a01.u = 0u; a23.u = 0u;
            #pragma unroll
            for (int e = 0; e < 9; ++e){
                float f = wt[e] * inv;
                if (e == 4) f += f;
                HU hf; hf.u = packhf(f, f);
                HU lo; lo.u = xv[e].x;
                HU hi; hi.u = xv[e].y;
                a01.h = __hfma2(hf.h, lo.h, a01.h);      // v_pk_fma_f16
                a23.h = __hfma2(hf.h, hi.h, a23.h);
            }
            const float a0 = __low2float(a01.h), a1 = __high2float(a01.h);
            const float a2 = __low2float(a23.h), a3 = __high2float(a23.h);

            float o0 = a0 + bi[0], o1 = a1 + bi[1], o2 = a2 + bi[2], o3 = a3 + bi[3];
            o0 = o0 > 0.f ? o0 : __expf(o0) - 1.f;
            o1 = o1 > 0.f ? o1 : __expf(o1) - 1.f;
            o2 = o2 > 0.f ? o2 : __expf(o2) - 1.f;
            o3 = o3 > 0.f ? o3 : __expf(o3) - 1.f;

            float sm = (o0 + o1) + (o2 + o3);
            float sq = o0*o0 + o1*o1 + o2*o2 + o3*o3;
            #pragma unroll
            for (int off = 1; off <= 16; off <<= 1){
                sm += __shfl_xor(sm, off, 64);
                sq += __shfl_xor(sq, off, 64);
            }
            const float mu  = sm * (1.f/128.f);
            float var = sq * (1.f/128.f) - mu*mu;
            var = var < 0.f ? 0.f : var;
            const float rstd = __builtin_amdgcn_rsqf(var + 1e-5f);
            outT[4*l2+0][nl] = (o0 - mu)*rstd*ga[0] + be[0];
            outT[4*l2+1][nl] = (o1 - mu)*rstd*ga[1] + be[1];
            outT[4*l2+2][nl] = (o2 - mu)*rstd*ga[2] + be[2];
            outT[4*l2+3][nl] = (o3 - mu)*rstd*ga[3] + be[3];
        }
    }
    #undef NODE
    __syncthreads();

    float* ob = out + (size_t)b*CCH*NNODE + n0;
    #pragma unroll
    for (int it = 0; it < 32; ++it){
        int c = it*4 + w;
        ob[(size_t)c*NNODE + lane] = outT[c][lane];
    }
}

extern "C" void kernel_launch(void* const* d_in, const int* in_sizes, int n_in,
                              void* d_out, int out_size, void* d_ws, size_t ws_size,
                              hipStream_t stream)
{
    const float* x    = (const float*)d_in[0];
    const float* Wl   = (const float*)d_in[1];
    const float* attS = (const float*)d_in[2];
    const float* attD = (const float*)d_in[3];
    const float* bias = (const float*)d_in[4];
    const float* gamma= (const float*)d_in[5];
    const float* beta = (const float*)d_in[6];
    float* out = (float*)d_out;

    __half* xpb = (__half*)d_ws;                                        // B*N*128 f16
    float*  scS = (float*)((char*)d_ws + (size_t)BATCH*NNODE*CCH*2);    // B*N*8 f32
    float*  scD = scS + (size_t)BATCH*NNODE*NHEAD;                      // B*N*8 f32

    kA<<<dim3(NNODE/128, BATCH), 256, 0, stream>>>(x, Wl, attS, attD, xpb, scS, scD);
    kB<<<dim3(NNODE/64,  BATCH), 256, 0, stream>>>(xpb, scS, scD, bias, gamma, beta, out);
}

// Round 3
// 117.903 us; speedup vs baseline: 1.0153x; 1.0153x over previous
//
#include <hip/hip_runtime.h>
#include <hip/hip_fp16.h>
#include <stdint.h>

#define BATCH  4
#define CCH    128
#define GRID_H 128
#define GRID_W 128
#define NNODE  (GRID_H*GRID_W)   // 16384
#define NHEAD  8
#define DH     16
#define WPAD   68                // padded k2 row (64 + 4), keeps b128 align
#define WROWS  144               // 128 ch + 8 aS + 8 aD

typedef __attribute__((ext_vector_type(8))) short short8;
typedef __attribute__((ext_vector_type(4))) float f32x4;
typedef __attribute__((ext_vector_type(4))) unsigned u32x4;

__device__ inline unsigned packbf(float a, float b){
    unsigned r;
    asm("v_cvt_pk_bf16_f32 %0, %1, %2" : "=v"(r) : "v"(a), "v"(b));
    return r;
}
__device__ inline unsigned packhf(float a, float b){
    unsigned r;
    asm("v_cvt_pkrtz_f16_f32 %0, %1, %2" : "=v"(r) : "v"(a), "v"(b));
    return r;
}

// ---------------------------------------------------------------------------
// kW (round-0 verbatim): pack augmented W' (144 cols: W | W@attS | W@attD) to
// bf16 k-pairs, co-major: Wb[co*WPAD + k2] = {bf16 W'[2k2][co], W'[2k2+1][co]}.
// Computed ONCE (16 blocks) instead of redundantly in all 512 kA blocks.
// ---------------------------------------------------------------------------
__global__ void kW(const float* __restrict__ Wl, const float* __restrict__ attS,
                   const float* __restrict__ attD, unsigned* __restrict__ Wb)
{
    __shared__ float Wa[8][16];
    const int t = threadIdx.x;
    const int cbase = blockIdx.x * 8;
    if (t < 128){
        int cl = t >> 4, j = t & 15;
        const float* av = (j < 8 ? attS + j*DH : attD + (j-8)*DH);
        const float* wr = Wl + (size_t)(cbase + cl)*CCH + (j & 7)*DH;
        float s = 0.f;
        #pragma unroll
        for (int d = 0; d < DH; ++d) s += wr[d]*av[d];
        Wa[cl][j] = s;
    }
    __syncthreads();
    for (int it = 0; it < 3; ++it){
        int flat = it*256 + t;
        if (flat < 576){
            int k2l = flat / 144, co = flat % 144;
            int k2 = blockIdx.x*4 + k2l;
            float w0, w1;
            if (co < CCH){
                w0 = Wl[(size_t)(2*k2)*CCH + co];
                w1 = Wl[(size_t)(2*k2+1)*CCH + co];
            } else {
                w0 = Wa[2*k2l][co-CCH];
                w1 = Wa[2*k2l+1][co-CCH];
            }
            Wb[co*WPAD + k2] = packbf(w0, w1);
        }
    }
}

// ---------------------------------------------------------------------------
// kA: 128-node tiles; W' staged from global via 10x u32x4 loads (39 KB LDS
// only); GEMM orientation and epilogue as verified in round 2 (f16 xp via
// v_cvt, split scS/scD, XCD band swizzle).
// ---------------------------------------------------------------------------
__global__ __launch_bounds__(256, 3) void kA(
    const float* __restrict__ x, const unsigned* __restrict__ Wbg,
    __half* __restrict__ xpb, float* __restrict__ scS, float* __restrict__ scD)
{
    __shared__ __align__(16) unsigned WbL[WROWS*WPAD];   // 39168 B

    const int t  = threadIdx.x;
    const int b  = blockIdx.y;
    const int bx = blockIdx.x;
    const int row = (bx & 7)*16 + (bx >> 3);             // bijective over 128 rows
    const int n0  = row * GRID_W;

    #pragma unroll
    for (int it = 0; it < 10; ++it){
        int f4 = it*256 + t;
        if (f4 < (WROWS*WPAD)/4)
            *(u32x4*)(&WbL[f4*4]) = *(const u32x4*)(Wbg + (size_t)f4*4);
    }
    __syncthreads();

    const int w = t >> 6, lane = t & 63;
    const int col = lane & 15, q = lane >> 4;
    const float* xb = x + (size_t)b*CCH*NNODE;
    const int nA = n0 + (2*w+0)*16 + col;
    const int nB = n0 + (2*w+1)*16 + col;

    f32x4 acc[2][9];
    #pragma unroll
    for (int mi = 0; mi < 2; ++mi)
        #pragma unroll
        for (int ct = 0; ct < 9; ++ct) acc[mi][ct] = (f32x4)(0.f);

    float xrA[8], xrB[8], x2A[8], x2B[8];
    #pragma unroll
    for (int j = 0; j < 8; ++j){
        const size_t co = (size_t)(q*8 + j)*NNODE;
        xrA[j] = xb[co + nA];
        xrB[j] = xb[co + nB];
    }

    union U { u32x4 u; short8 s; };
    #pragma unroll
    for (int kc = 0; kc < 4; ++kc){
        if (kc < 3){
            #pragma unroll
            for (int j = 0; j < 8; ++j){
                const size_t co = (size_t)((kc+1)*32 + q*8 + j)*NNODE;
                x2A[j] = xb[co + nA];
                x2B[j] = xb[co + nB];
            }
        }
        U fa0, fa1;
        #pragma unroll
        for (int i = 0; i < 4; ++i){
            fa0.u[i] = packbf(xrA[2*i], xrA[2*i+1]);
            fa1.u[i] = packbf(xrB[2*i], xrB[2*i+1]);
        }
        const int kof = kc*16 + q*4;
        #pragma unroll
        for (int ct = 0; ct < 9; ++ct){
            U fb; fb.u = *(const u32x4*)(&WbL[(ct*16+col)*WPAD + kof]);
            acc[0][ct] = __builtin_amdgcn_mfma_f32_16x16x32_bf16(fa0.s, fb.s, acc[0][ct], 0, 0, 0);
            acc[1][ct] = __builtin_amdgcn_mfma_f32_16x16x32_bf16(fa1.s, fb.s, acc[1][ct], 0, 0, 0);
        }
        #pragma unroll
        for (int j = 0; j < 8; ++j){ xrA[j] = x2A[j]; xrB[j] = x2B[j]; }
    }

    // epilogue (round-2 verified): D layout col=lane&15 -> channel, q*4+r -> node
    __half* xr = xpb + (size_t)b*NNODE*CCH;
    float*  sS = scS + (size_t)b*NNODE*NHEAD;
    float*  sD = scD + (size_t)b*NNODE*NHEAD;
    #pragma unroll
    for (int mi = 0; mi < 2; ++mi){
        #pragma unroll
        for (int r = 0; r < 4; ++r){
            const int n = n0 + (2*w+mi)*16 + q*4 + r;
            #pragma unroll
            for (int ct = 0; ct < 8; ++ct)
                xr[(size_t)n*CCH + ct*16 + col] = __float2half(acc[mi][ct][r]);
            const float v = acc[mi][8][r];               // aug index j = col
            if (col < 8) sS[(size_t)n*NHEAD + col]     = v;
            else         sD[(size_t)n*NHEAD + col - 8] = v;
        }
    }
}

// ---------------------------------------------------------------------------
// kB (round-2 verified) with __launch_bounds__(256,4): all 1024 blocks
// co-resident (single generation, was 1.33), 16 waves/CU for gather hiding.
// ---------------------------------------------------------------------------
__device__ inline void kb_issue(int n, const float* __restrict__ scSb,
                                const float* __restrict__ scDb,
                                const uint2* __restrict__ xvb, int h, int l2,
                                int* vm, float aS[9], float* aD, uint2 xv[9])
{
    const int rr = n >> 7, cc = n & 127;
    const bool vU = rr > 0, vD = rr < GRID_H-1, vL = cc > 0, vR = cc < GRID_W-1;
    int m = 0;
    #pragma unroll
    for (int e = 0; e < 9; ++e){
        const int dr = e/3 - 1, dc = e%3 - 1;
        const bool vr_ = (dr < 0) ? vU : (dr > 0 ? vD : true);
        const bool vc_ = (dc < 0) ? vL : (dc > 0 ? vR : true);
        const bool v = vr_ && vc_;
        const int src = v ? (n + dr*GRID_W + dc) : n;
        m |= ((int)v) << e;
        aS[e] = scSb[src*NHEAD + h];
        xv[e] = xvb[(size_t)src*32 + l2];
    }
    *aD = scDb[n*NHEAD + h];
    *vm = m;
}

__global__ __launch_bounds__(256, 4) void kB(
    const __half* __restrict__ xpb, const float* __restrict__ scS,
    const float* __restrict__ scD,
    const float* __restrict__ bias, const float* __restrict__ gamma,
    const float* __restrict__ beta, float* __restrict__ out)
{
    __shared__ float outT[CCH][65];
    const int t = threadIdx.x, w = t >> 6, lane = t & 63;
    const int h2 = lane >> 5, l2 = lane & 31;
    const int b  = blockIdx.y;
    const int bx = blockIdx.x;
    const int xcd = bx & 7, rest = bx >> 3;
    const int hlf = rest & 1, rowin = rest >> 1;
    const int n0  = (xcd*16 + rowin)*GRID_W + hlf*64;    // bijective over 256 blocks

    const uint2* xvb  = (const uint2*)(xpb + (size_t)b*NNODE*CCH);
    const float* scSb = scS + (size_t)b*NNODE*NHEAD;
    const float* scDb = scD + (size_t)b*NNODE*NHEAD;
    const int h = l2 >> 2;
    const f32x4 bi = *(const f32x4*)(bias  + 4*l2);
    const f32x4 ga = *(const f32x4*)(gamma + 4*l2);
    const f32x4 be = *(const f32x4*)(beta  + 4*l2);

    float aSP[2][9]; uint2 xvP[2][9]; float aDP[2]; int vmP[2];

    #define NODE(i) (n0 + w*16 + 2*(i) + h2)
    kb_issue(NODE(0), scSb, scDb, xvb, h, l2, &vmP[0], aSP[0], &aDP[0], xvP[0]);

    #pragma unroll
    for (int ii = 0; ii < 4; ++ii){
        #pragma unroll
        for (int ph = 0; ph < 2; ++ph){
            const int i = 2*ii + ph;
            const int cur = i & 1;
            if (i + 1 < 8)
                kb_issue(NODE(i+1), scSb, scDb, xvb, h, l2,
                         &vmP[cur^1], aSP[cur^1], &aDP[cur^1], xvP[cur^1]);

            const int vm = vmP[cur];
            const float* aS = aSP[cur];
            const uint2*  xv = xvP[cur];
            const float ad = aDP[cur];
            const int nl = w*16 + 2*i + h2;

            float s[9], mx = -1e30f;
            #pragma unroll
            for (int e = 0; e < 9; ++e){
                float sv = aS[e] + ad;
                sv = fmaxf(sv, 0.2f*sv);
                s[e] = ((vm >> e) & 1) ? sv : -1e30f;
                mx = fmaxf(mx, s[e]);
            }
            float wt[9], den = 0.f;
            #pragma unroll
            for (int e = 0; e < 9; ++e){
                float ex = __expf(s[e] - mx);
                ex = ((vm >> e) & 1) ? ex : 0.f;
                wt[e] = ex; den += ex;
            }
            den += wt[4];                                // add_self_loops duplicate
            const float inv = __builtin_amdgcn_rcpf(den);

            union HU { unsigned u; __half2 h; };
            HU a01, a23; a01.u = 0u; a23.u = 0u;
            #pragma unroll
            for (int e = 0; e < 9; ++e){
                float f = wt[e] * inv;
                if (e == 4) f += f;
                HU hf; hf.u = packhf(f, f);
                HU lo; lo.u = xv[e].x;
                HU hi; hi.u = xv[e].y;
                a01.h = __hfma2(hf.h, lo.h, a01.h);      // v_pk_fma_f16
                a23.h = __hfma2(hf.h, hi.h, a23.h);
            }
            const float a0 = __low2float(a01.h), a1 = __high2float(a01.h);
            const float a2 = __low2float(a23.h), a3 = __high2float(a23.h);

            float o0 = a0 + bi[0], o1 = a1 + bi[1], o2 = a2 + bi[2], o3 = a3 + bi[3];
            o0 = o0 > 0.f ? o0 : __expf(o0) - 1.f;
            o1 = o1 > 0.f ? o1 : __expf(o1) - 1.f;
            o2 = o2 > 0.f ? o2 : __expf(o2) - 1.f;
            o3 = o3 > 0.f ? o3 : __expf(o3) - 1.f;

            float sm = (o0 + o1) + (o2 + o3);
            float sq = o0*o0 + o1*o1 + o2*o2 + o3*o3;
            #pragma unroll
            for (int off = 1; off <= 16; off <<= 1){
                sm += __shfl_xor(sm, off, 64);
                sq += __shfl_xor(sq, off, 64);
            }
            const float mu  = sm * (1.f/128.f);
            float var = sq * (1.f/128.f) - mu*mu;
            var = var < 0.f ? 0.f : var;
            const float rstd = __builtin_amdgcn_rsqf(var + 1e-5f);
            outT[4*l2+0][nl] = (o0 - mu)*rstd*ga[0] + be[0];
            outT[4*l2+1][nl] = (o1 - mu)*rstd*ga[1] + be[1];
            outT[4*l2+2][nl] = (o2 - mu)*rstd*ga[2] + be[2];
            outT[4*l2+3][nl] = (o3 - mu)*rstd*ga[3] + be[3];
        }
    }
    #undef NODE
    __syncthreads();

    float* ob = out + (size_t)b*CCH*NNODE + n0;
    #pragma unroll
    for (int it = 0; it < 32; ++it){
        int c = it*4 + w;
        ob[(size_t)c*NNODE + lane] = outT[c][lane];
    }
}

extern "C" void kernel_launch(void* const* d_in, const int* in_sizes, int n_in,
                              void* d_out, int out_size, void* d_ws, size_t ws_size,
                              hipStream_t stream)
{
    const float* x    = (const float*)d_in[0];
    const float* Wl   = (const float*)d_in[1];
    const float* attS = (const float*)d_in[2];
    const float* attD = (const float*)d_in[3];
    const float* bias = (const float*)d_in[4];
    const float* gamma= (const float*)d_in[5];
    const float* beta = (const float*)d_in[6];
    float* out = (float*)d_out;

    __half* xpb = (__half*)d_ws;                                        // B*N*128 f16
    float*  scS = (float*)((char*)d_ws + (size_t)BATCH*NNODE*CCH*2);    // B*N*8 f32
    float*  scD = scS + (size_t)BATCH*NNODE*NHEAD;                      // B*N*8 f32
    unsigned* Wb = (unsigned*)(scD + (size_t)BATCH*NNODE*NHEAD);        // 144*68 u32

    kW<<<dim3(16),               256, 0, stream>>>(Wl, attS, attD, Wb);
    kA<<<dim3(NNODE/128, BATCH), 256, 0, stream>>>(x, Wb, xpb, scS, scD);
    kB<<<dim3(NNODE/64,  BATCH), 256, 0, stream>>>(xpb, scS, scD, bias, gamma, beta, out);
}